// Round 1
// baseline (143.702 us; speedup 1.0000x reference)
//
#include <hip/hip_runtime.h>
#include <math.h>

#define N0 200000
#define N1 1024
#define N2 256
#define N3 32
#define NE0 2048000
#define NE1 262144
#define NE2 8192
#define BATCH 32
#define NCLS 10

__device__ __forceinline__ int lower_bound_i(const int* __restrict__ a, int n, int key) {
    int lo = 0, hi = n;
    while (lo < hi) {
        int mid = (lo + hi) >> 1;
        if (a[mid] < key) lo = mid + 1; else hi = mid;
    }
    return lo;
}

// x (32, 200000) row-major -> xt (200000, 32) row-major, LDS tiled.
__global__ __launch_bounds__(256) void k_transpose(const float* __restrict__ x,
                                                   float* __restrict__ xt) {
    __shared__ float tile[32][65];
    const int col0 = blockIdx.x * 64;
    const int tid = threadIdx.x;
    const int c = tid & 63, r0 = tid >> 6;       // 4 row-lanes
    #pragma unroll
    for (int r = r0; r < 32; r += 4) {
        int col = col0 + c;
        tile[r][c] = (col < N0) ? x[r * N0 + col] : 0.f;
    }
    __syncthreads();
    const int b = tid & 31, c0 = tid >> 5;       // 8 col-lanes
    #pragma unroll
    for (int cc = c0; cc < 64; cc += 8) {
        int col = col0 + cc;
        if (col < N0) xt[col * 32 + b] = tile[b][cc];
    }
}

// Segmented gather-sum: out[n][0..31] = sum_{e: dst[e]==n} table[src[e]][0..31]
// table rows are 32 floats (8 float4). One block per output segment (dst sorted).
// Optional: cnt_out[n] = segment length; t_out[n] = sum cnt_in[src[e]].
__global__ __launch_bounds__(256) void k_gather(const float4* __restrict__ table,
                                                const int* __restrict__ src,
                                                const int* __restrict__ dst,
                                                int nedges,
                                                float* __restrict__ out,
                                                const float* __restrict__ cnt_in,
                                                float* __restrict__ cnt_out,
                                                float* __restrict__ t_out) {
    const int n = blockIdx.x;
    const int e0 = lower_bound_i(dst, nedges, n);
    const int e1 = lower_bound_i(dst, nedges, n + 1);
    const int tid = threadIdx.x;
    const int b4 = tid & 7;       // which float4 of the 32-float row
    const int g  = tid >> 3;      // 32 edge groups
    float4 acc = make_float4(0.f, 0.f, 0.f, 0.f);
    float tacc = 0.f;
    for (int e = e0 + g; e < e1; e += 32) {
        int s = src[e];
        float4 v = table[s * 8 + b4];
        acc.x += v.x; acc.y += v.y; acc.z += v.z; acc.w += v.w;
        if (cnt_in != nullptr && b4 == 0) tacc += cnt_in[s];
    }
    __shared__ float4 red[32][8];
    __shared__ float tred[32];
    red[g][b4] = acc;
    if (b4 == 0) tred[g] = tacc;
    __syncthreads();
    if (tid < 8) {
        float4 s = red[0][tid];
        #pragma unroll
        for (int i = 1; i < 32; ++i) {
            float4 v = red[i][tid];
            s.x += v.x; s.y += v.y; s.z += v.z; s.w += v.w;
        }
        reinterpret_cast<float4*>(out)[n * 8 + tid] = s;
    } else if (tid == 8 && cnt_out != nullptr) {
        cnt_out[n] = (float)(e1 - e0);
    } else if (tid == 9 && t_out != nullptr) {
        float s = 0.f;
        #pragma unroll
        for (int i = 0; i < 32; ++i) s += tred[i];
        t_out[n] = s;
    }
}

// All weight algebra + final output. Single block, 320 threads (5 waves).
__global__ __launch_bounds__(320) void k_finale(
    const float* __restrict__ V0, const float* __restrict__ g0, const float* __restrict__ b0,
    const float* __restrict__ V1, const float* __restrict__ g1, const float* __restrict__ b1,
    const float* __restrict__ V2, const float* __restrict__ g2, const float* __restrict__ b2,
    const float* __restrict__ Vfc, const float* __restrict__ gfc, const float* __restrict__ bfc,
    const float* __restrict__ S2, const float* __restrict__ T2, const float* __restrict__ cnt2,
    float* __restrict__ out) {
    __shared__ float w0[32], u[64], v[64], p[128], q[128], r[128];
    __shared__ float M[10][32], Kc[10], nrmfc[10];
    const int tid = threadIdx.x;

    // w0[c] = g0[c] * V0[c,0] / |V0[c,0]|   (C_in = 1 -> norm is abs)
    if (tid < 32) {
        float val = V0[tid];
        w0[tid] = g0[tid] * val / fabsf(val);
    }
    __syncthreads();

    // u = W1n @ w0, v = W1n @ b0    (W1n: 64x32 weight-normed V1)
    if (tid < 64) {
        float nn = 0.f;
        #pragma unroll
        for (int c = 0; c < 32; ++c) { float t = V1[tid * 32 + c]; nn += t * t; }
        float inv = g1[tid] * rsqrtf(nn);
        float su = 0.f, sv = 0.f;
        #pragma unroll
        for (int c = 0; c < 32; ++c) {
            float w = V1[tid * 32 + c] * inv;
            su += w * w0[c]; sv += w * b0[c];
        }
        u[tid] = su; v[tid] = sv;
    }
    __syncthreads();

    // p = W2n @ u, q = W2n @ v, r = W2n @ b1   (W2n: 128x64)
    if (tid < 128) {
        float nn = 0.f;
        #pragma unroll
        for (int c = 0; c < 64; ++c) { float t = V2[tid * 64 + c]; nn += t * t; }
        float inv = g2[tid] * rsqrtf(nn);
        float sp = 0.f, sq = 0.f, sr = 0.f;
        #pragma unroll
        for (int c = 0; c < 64; ++c) {
            float w = V2[tid * 64 + c] * inv;
            sp += w * u[c]; sq += w * v[c]; sr += w * b1[c];
        }
        p[tid] = sp; q[tid] = sq; r[tid] = sr;
    }
    // Vfc row norms (10 rows x 4096), 32 lanes per row; independent of p/q/r.
    {
        int k = tid >> 5, l = tid & 31;
        if (k < 10) {
            float s = 0.f;
            for (int j = l; j < 4096; j += 32) { float t = Vfc[k * 4096 + j]; s += t * t; }
            #pragma unroll
            for (int off = 16; off; off >>= 1) s += __shfl_xor(s, off);
            if (l == 0) nrmfc[k] = sqrtf(s);
        }
    }
    __syncthreads();

    // M[k][n3] and Kc[k]
    {
        int k = tid >> 5, n3 = tid & 31;
        if (k < 10) {
            float mk = 0.f, mq = 0.f, mr = 0.f, mb = 0.f;
            #pragma unroll 4
            for (int o = 0; o < 128; ++o) {
                float w = Vfc[k * 4096 + o * 32 + n3];
                mk += w * p[o]; mq += w * q[o]; mr += w * r[o]; mb += w * b2[o];
            }
            float scale = gfc[k] / nrmfc[k];
            M[k][n3] = scale * mk;
            float kcp = scale * (mq * T2[n3] + mr * cnt2[n3] + mb);
            #pragma unroll
            for (int off = 16; off; off >>= 1) kcp += __shfl_xor(kcp, off);
            if (n3 == 0) Kc[k] = kcp + bfc[k];
        }
    }
    __syncthreads();

    // out[b,k] = sum_n3 M[k][n3] * S2[n3,b] + Kc[k]
    {
        int k = tid >> 5, b = tid & 31;
        if (k < 10) {
            float s = 0.f;
            #pragma unroll
            for (int n3 = 0; n3 < 32; ++n3) s += M[k][n3] * S2[n3 * 32 + b];
            out[b * NCLS + k] = s + Kc[k];
        }
    }
}

extern "C" void kernel_launch(void* const* d_in, const int* in_sizes, int n_in,
                              void* d_out, int out_size, void* d_ws, size_t ws_size,
                              hipStream_t stream) {
    const float* x   = (const float*)d_in[0];
    const int* src0  = (const int*)d_in[1];
    const int* dst0  = (const int*)d_in[2];
    const int* src1  = (const int*)d_in[3];
    const int* dst1  = (const int*)d_in[4];
    const int* src2  = (const int*)d_in[5];
    const int* dst2  = (const int*)d_in[6];
    const float* V0  = (const float*)d_in[7];
    const float* g0  = (const float*)d_in[8];
    const float* b0  = (const float*)d_in[9];
    const float* V1  = (const float*)d_in[10];
    const float* g1  = (const float*)d_in[11];
    const float* b1  = (const float*)d_in[12];
    const float* V2  = (const float*)d_in[13];
    const float* g2  = (const float*)d_in[14];
    const float* b2  = (const float*)d_in[15];
    const float* Vfc = (const float*)d_in[16];
    const float* gfc = (const float*)d_in[17];
    const float* bfc = (const float*)d_in[18];

    char* ws = (char*)d_ws;
    float* xt   = (float*)(ws);                      // 200000*32*4 = 25,600,000 B
    float* P0   = (float*)(ws + 25600000);           // 1024*32*4   = 131,072 B
    float* S1   = (float*)(ws + 25731072);           // 256*32*4    = 32,768 B
    float* cnt1 = (float*)(ws + 25763840);           // 256*4       = 1,024 B
    float* S2   = (float*)(ws + 25764864);           // 32*32*4     = 4,096 B
    float* T2   = (float*)(ws + 25768960);           // 32*4        = 128 B
    float* cnt2 = (float*)(ws + 25769088);           // 32*4        = 128 B

    k_transpose<<<(N0 + 63) / 64, 256, 0, stream>>>(x, xt);
    k_gather<<<N1, 256, 0, stream>>>((const float4*)xt, src0, dst0, NE0, P0,
                                     nullptr, nullptr, nullptr);
    k_gather<<<N2, 256, 0, stream>>>((const float4*)P0, src1, dst1, NE1, S1,
                                     nullptr, cnt1, nullptr);
    k_gather<<<N3, 256, 0, stream>>>((const float4*)S1, src2, dst2, NE2, S2,
                                     cnt1, cnt2, T2);
    k_finale<<<1, 320, 0, stream>>>(V0, g0, b0, V1, g1, b1, V2, g2, b2,
                                    Vfc, gfc, bfc, S2, T2, cnt2, (float*)d_out);
}

// Round 2
// 108.682 us; speedup vs baseline: 1.3222x; 1.3222x over previous
//
#include <hip/hip_runtime.h>
#include <math.h>

#define N0 200000
#define N1 1024
#define N2 256
#define N3 32
#define NE0 2048000
#define NE1 262144
#define NE2 8192
#define BATCH 32
#define NCLS 10

__device__ __forceinline__ int lower_bound_i(const int* __restrict__ a, int n, int key) {
    int lo = 0, hi = n;
    while (lo < hi) {
        int mid = (lo + hi) >> 1;
        if (a[mid] < key) lo = mid + 1; else hi = mid;
    }
    return lo;
}

// x (32, 200000) row-major -> xt (200000, 32) row-major, LDS tiled.
__global__ __launch_bounds__(256) void k_transpose(const float* __restrict__ x,
                                                   float* __restrict__ xt) {
    __shared__ float tile[32][65];
    const int col0 = blockIdx.x * 64;
    const int tid = threadIdx.x;
    const int c = tid & 63, r0 = tid >> 6;       // 4 row-lanes
    #pragma unroll
    for (int r = r0; r < 32; r += 4) {
        int col = col0 + c;
        tile[r][c] = (col < N0) ? x[r * N0 + col] : 0.f;
    }
    __syncthreads();
    const int b = tid & 31, c0 = tid >> 5;       // 8 col-lanes
    #pragma unroll
    for (int cc = c0; cc < 64; cc += 8) {
        int col = col0 + cc;
        if (col < N0) xt[col * 32 + b] = tile[b][cc];
    }
}

// Segmented gather-sum: out[n][0..31] = sum_{e: dst[e]==n} table[src[e]][0..31]
// table rows are 32 floats (8 float4). One block per output segment (dst sorted).
// Optional: cnt_out[n] = segment length; t_out[n] = sum cnt_in[src[e]].
__global__ __launch_bounds__(256) void k_gather(const float4* __restrict__ table,
                                                const int* __restrict__ src,
                                                const int* __restrict__ dst,
                                                int nedges,
                                                float* __restrict__ out,
                                                const float* __restrict__ cnt_in,
                                                float* __restrict__ cnt_out,
                                                float* __restrict__ t_out) {
    const int n = blockIdx.x;
    const int e0 = lower_bound_i(dst, nedges, n);
    const int e1 = lower_bound_i(dst, nedges, n + 1);
    const int tid = threadIdx.x;
    const int b4 = tid & 7;       // which float4 of the 32-float row
    const int g  = tid >> 3;      // 32 edge groups
    float4 acc = make_float4(0.f, 0.f, 0.f, 0.f);
    float tacc = 0.f;
    for (int e = e0 + g; e < e1; e += 32) {
        int s = src[e];
        float4 v = table[s * 8 + b4];
        acc.x += v.x; acc.y += v.y; acc.z += v.z; acc.w += v.w;
        if (cnt_in != nullptr && b4 == 0) tacc += cnt_in[s];
    }
    __shared__ float4 red[32][8];
    __shared__ float tred[32];
    red[g][b4] = acc;
    if (b4 == 0) tred[g] = tacc;
    __syncthreads();
    if (tid < 8) {
        float4 s = red[0][tid];
        #pragma unroll
        for (int i = 1; i < 32; ++i) {
            float4 v = red[i][tid];
            s.x += v.x; s.y += v.y; s.z += v.z; s.w += v.w;
        }
        reinterpret_cast<float4*>(out)[n * 8 + tid] = s;
    } else if (tid == 8 && cnt_out != nullptr) {
        cnt_out[n] = (float)(e1 - e0);
    } else if (tid == 9 && t_out != nullptr) {
        float s = 0.f;
        #pragma unroll
        for (int i = 0; i < 32; ++i) s += tred[i];
        t_out[n] = s;
    }
}

// Weight algebra + final output. One block per class k (10 blocks, 256 threads).
// Each block redundantly computes the tiny weight chain, then a single coalesced
// pass over Vfc row k produces norm + M + Kc + out[:,k].
__global__ __launch_bounds__(256) void k_out(
    const float* __restrict__ V0, const float* __restrict__ g0, const float* __restrict__ b0,
    const float* __restrict__ V1, const float* __restrict__ g1, const float* __restrict__ b1,
    const float* __restrict__ V2, const float* __restrict__ g2, const float* __restrict__ b2,
    const float* __restrict__ Vfc, const float* __restrict__ gfc, const float* __restrict__ bfc,
    const float* __restrict__ S2, const float* __restrict__ T2, const float* __restrict__ cnt2,
    float* __restrict__ out) {
    const int k = blockIdx.x;
    const int tid = threadIdx.x;
    __shared__ float w0[32], u[64], v[64], p[128], q[128], r[128];
    __shared__ float redA[8][32], redB[8][32], redC[8][32], redD[8][32];
    __shared__ float nnred[4];
    __shared__ float M[32];
    __shared__ float scale_s, Kc_s;

    // --- weight chain (redundant per block, cheap) ---
    if (tid < 32) {
        float val = V0[tid];
        w0[tid] = g0[tid] * val / fabsf(val);
    }
    __syncthreads();
    if (tid < 64) {
        float nn = 0.f;
        #pragma unroll
        for (int c = 0; c < 32; ++c) { float t = V1[tid * 32 + c]; nn += t * t; }
        float inv = g1[tid] * rsqrtf(nn);
        float su = 0.f, sv = 0.f;
        #pragma unroll
        for (int c = 0; c < 32; ++c) {
            float w = V1[tid * 32 + c] * inv;
            su += w * w0[c]; sv += w * b0[c];
        }
        u[tid] = su; v[tid] = sv;
    }
    __syncthreads();
    if (tid < 128) {
        float nn = 0.f;
        #pragma unroll
        for (int c = 0; c < 64; ++c) { float t = V2[tid * 64 + c]; nn += t * t; }
        float inv = g2[tid] * rsqrtf(nn);
        float sp = 0.f, sq = 0.f, sr = 0.f;
        #pragma unroll
        for (int c = 0; c < 64; ++c) {
            float w = V2[tid * 64 + c] * inv;
            sp += w * u[c]; sq += w * v[c]; sr += w * b1[c];
        }
        p[tid] = sp; q[tid] = sq; r[tid] = sr;
    }
    __syncthreads();

    // --- single coalesced pass over Vfc row k ---
    // thread t owns n3 = t&31, o-group og = t>>5; o = og + 8*i, i = 0..15
    // address: k*4096 + o*32 + n3 = k*4096 + t + 256*i  (coalesced)
    const int n3 = tid & 31, og = tid >> 5;
    float nn = 0.f, mk = 0.f, mq = 0.f, mr = 0.f, mb = 0.f;
    #pragma unroll
    for (int i = 0; i < 16; ++i) {
        int o = og + 8 * i;
        float w = Vfc[k * 4096 + tid + 256 * i];
        nn += w * w;
        mk += w * p[o]; mq += w * q[o]; mr += w * r[o]; mb += w * b2[o];
    }
    // reduce nn across block
    #pragma unroll
    for (int off = 32; off; off >>= 1) nn += __shfl_xor(nn, off);
    if ((tid & 63) == 0) nnred[tid >> 6] = nn;
    // reduce mk/mq/mr/mb across the 8 o-groups per n3
    redA[og][n3] = mk; redB[og][n3] = mq; redC[og][n3] = mr; redD[og][n3] = mb;
    __syncthreads();
    if (tid == 0) {
        float s = nnred[0] + nnred[1] + nnred[2] + nnred[3];
        scale_s = gfc[k] * rsqrtf(s);
    }
    __syncthreads();
    if (tid < 32) {
        float smk = 0.f, smq = 0.f, smr = 0.f, smb = 0.f;
        #pragma unroll
        for (int i = 0; i < 8; ++i) {
            smk += redA[i][tid]; smq += redB[i][tid];
            smr += redC[i][tid]; smb += redD[i][tid];
        }
        float scale = scale_s;
        M[tid] = scale * smk;
        float kcp = scale * (smq * T2[tid] + smr * cnt2[tid] + smb);
        #pragma unroll
        for (int off = 16; off; off >>= 1) kcp += __shfl_xor(kcp, off);
        if (tid == 0) Kc_s = kcp + bfc[k];
    }
    __syncthreads();
    // out[b,k] = sum_n3 M[n3] * S2[n3,b] + Kc
    if (tid < 32) {
        int b = tid;
        float s = 0.f;
        #pragma unroll
        for (int n = 0; n < 32; ++n) s += M[n] * S2[n * 32 + b];
        out[b * NCLS + k] = s + Kc_s;
    }
}

extern "C" void kernel_launch(void* const* d_in, const int* in_sizes, int n_in,
                              void* d_out, int out_size, void* d_ws, size_t ws_size,
                              hipStream_t stream) {
    const float* x   = (const float*)d_in[0];
    const int* src0  = (const int*)d_in[1];
    const int* dst0  = (const int*)d_in[2];
    const int* src1  = (const int*)d_in[3];
    const int* dst1  = (const int*)d_in[4];
    const int* src2  = (const int*)d_in[5];
    const int* dst2  = (const int*)d_in[6];
    const float* V0  = (const float*)d_in[7];
    const float* g0  = (const float*)d_in[8];
    const float* b0  = (const float*)d_in[9];
    const float* V1  = (const float*)d_in[10];
    const float* g1  = (const float*)d_in[11];
    const float* b1  = (const float*)d_in[12];
    const float* V2  = (const float*)d_in[13];
    const float* g2  = (const float*)d_in[14];
    const float* b2  = (const float*)d_in[15];
    const float* Vfc = (const float*)d_in[16];
    const float* gfc = (const float*)d_in[17];
    const float* bfc = (const float*)d_in[18];

    char* ws = (char*)d_ws;
    float* xt   = (float*)(ws);                      // 200000*32*4 = 25,600,000 B
    float* P0   = (float*)(ws + 25600000);           // 1024*32*4   = 131,072 B
    float* S1   = (float*)(ws + 25731072);           // 256*32*4    = 32,768 B
    float* cnt1 = (float*)(ws + 25763840);           // 256*4       = 1,024 B
    float* S2   = (float*)(ws + 25764864);           // 32*32*4     = 4,096 B
    float* T2   = (float*)(ws + 25768960);           // 32*4        = 128 B
    float* cnt2 = (float*)(ws + 25769088);           // 32*4        = 128 B

    k_transpose<<<(N0 + 63) / 64, 256, 0, stream>>>(x, xt);
    k_gather<<<N1, 256, 0, stream>>>((const float4*)xt, src0, dst0, NE0, P0,
                                     nullptr, nullptr, nullptr);
    k_gather<<<N2, 256, 0, stream>>>((const float4*)P0, src1, dst1, NE1, S1,
                                     nullptr, cnt1, nullptr);
    k_gather<<<N3, 256, 0, stream>>>((const float4*)S1, src2, dst2, NE2, S2,
                                     cnt1, cnt2, T2);
    k_out<<<NCLS, 256, 0, stream>>>(V0, g0, b0, V1, g1, b1, V2, g2, b2,
                                    Vfc, gfc, bfc, S2, T2, cnt2, (float*)d_out);
}

// Round 3
// 86.212 us; speedup vs baseline: 1.6668x; 1.2606x over previous
//
#include <hip/hip_runtime.h>
#include <math.h>

#define N0 200000
#define N1 1024
#define N2 256
#define N3 32
#define NE0 2048000
#define NE1 262144
#define NE2 8192
#define BATCH 32
#define NCLS 10

typedef _Float16 h2 __attribute__((ext_vector_type(2)));
typedef _Float16 h8 __attribute__((ext_vector_type(8)));

__device__ __forceinline__ int lower_bound_i(const int* __restrict__ a, int n, int key) {
    int lo = 0, hi = n;
    while (lo < hi) {
        int mid = (lo + hi) >> 1;
        if (a[mid] < key) lo = mid + 1; else hi = mid;
    }
    return lo;
}

// x (32, 200000) fp32 -> xt (200000, 32) fp16 rows (64 B each), LDS tiled.
__global__ __launch_bounds__(256) void k_transpose(const float* __restrict__ x,
                                                   h2* __restrict__ xt) {
    __shared__ float tile[32][65];
    const int col0 = blockIdx.x * 64;
    const int tid = threadIdx.x;
    const int c = tid & 63, r0 = tid >> 6;       // 4 row-lanes
    #pragma unroll
    for (int r = r0; r < 32; r += 4) {
        int col = col0 + c;
        tile[r][c] = (col < N0) ? x[r * N0 + col] : 0.f;
    }
    __syncthreads();
    const int bb = (tid & 15) * 2, c0 = tid >> 4; // 16 col-lanes, 2 batch rows/thread
    #pragma unroll
    for (int cc = c0; cc < 64; cc += 16) {
        int col = col0 + cc;
        if (col < N0) {
            h2 v;
            v[0] = (_Float16)tile[bb][cc];
            v[1] = (_Float16)tile[bb + 1][cc];
            xt[col * 16 + (bb >> 1)] = v;
        }
    }
}

// Segmented gather-sum over fp16 rows (32 halves = 64 B = 4 x h8).
// out[n][0..31] = sum_{e: dst[e]==n} table[src[e]][0..31], fp32 accumulation.
// One block per output segment (dst sorted, two binary searches).
// out_h: fp16 row output (next gather's table); out_f: fp32 output.
// Optional: cnt_out[n] = segment length; t_out[n] = sum cnt_in[src[e]].
__global__ __launch_bounds__(256) void k_gather(const h8* __restrict__ table,
                                                const int* __restrict__ src,
                                                const int* __restrict__ dst,
                                                int nedges,
                                                _Float16* __restrict__ out_h,
                                                float* __restrict__ out_f,
                                                const float* __restrict__ cnt_in,
                                                float* __restrict__ cnt_out,
                                                float* __restrict__ t_out) {
    const int n = blockIdx.x;
    const int e0 = lower_bound_i(dst, nedges, n);
    const int e1 = lower_bound_i(dst, nedges, n + 1);
    const int tid = threadIdx.x;
    const int b4 = tid & 3;       // which 16B chunk of the 64B row
    const int g  = tid >> 2;      // 64 edge groups
    float acc[8] = {0.f, 0.f, 0.f, 0.f, 0.f, 0.f, 0.f, 0.f};
    float tacc = 0.f;
    for (int e = e0 + g; e < e1; e += 64) {
        int s = src[e];
        h8 v = table[s * 4 + b4];
        #pragma unroll
        for (int i = 0; i < 8; ++i) acc[i] += (float)v[i];
        if (cnt_in != nullptr && b4 == 0) tacc += cnt_in[s];
    }
    __shared__ float red[64][33];
    __shared__ float tred[64];
    #pragma unroll
    for (int i = 0; i < 8; ++i) red[g][b4 * 8 + i] = acc[i];
    if (b4 == 0) tred[g] = tacc;
    __syncthreads();
    #pragma unroll
    for (int s = 32; s >= 1; s >>= 1) {
        if (g < s) {
            #pragma unroll
            for (int i = 0; i < 8; ++i)
                red[g][b4 * 8 + i] += red[g + s][b4 * 8 + i];
            if (b4 == 0) tred[g] += tred[g + s];
        }
        __syncthreads();
    }
    if (tid < 32) {
        float v = red[0][tid];
        if (out_h != nullptr) out_h[n * 32 + tid] = (_Float16)v;
        if (out_f != nullptr) out_f[n * 32 + tid] = v;
    } else if (tid == 32 && cnt_out != nullptr) {
        cnt_out[n] = (float)(e1 - e0);
    } else if (tid == 33 && t_out != nullptr) {
        t_out[n] = tred[0];
    }
}

// Weight algebra + final output. One block per class k (10 blocks, 256 threads).
__global__ __launch_bounds__(256) void k_out(
    const float* __restrict__ V0, const float* __restrict__ g0, const float* __restrict__ b0,
    const float* __restrict__ V1, const float* __restrict__ g1, const float* __restrict__ b1,
    const float* __restrict__ V2, const float* __restrict__ g2, const float* __restrict__ b2,
    const float* __restrict__ Vfc, const float* __restrict__ gfc, const float* __restrict__ bfc,
    const float* __restrict__ S2, const float* __restrict__ T2, const float* __restrict__ cnt2,
    float* __restrict__ out) {
    const int k = blockIdx.x;
    const int tid = threadIdx.x;
    __shared__ float w0[32], u[64], v[64], p[128], q[128], r[128];
    __shared__ float redA[8][32], redB[8][32], redC[8][32], redD[8][32];
    __shared__ float nnred[4];
    __shared__ float M[32];
    __shared__ float scale_s, Kc_s;

    // --- weight chain (redundant per block, cheap) ---
    if (tid < 32) {
        float val = V0[tid];
        w0[tid] = g0[tid] * val / fabsf(val);
    }
    __syncthreads();
    if (tid < 64) {
        float nn = 0.f;
        #pragma unroll
        for (int c = 0; c < 32; ++c) { float t = V1[tid * 32 + c]; nn += t * t; }
        float inv = g1[tid] * rsqrtf(nn);
        float su = 0.f, sv = 0.f;
        #pragma unroll
        for (int c = 0; c < 32; ++c) {
            float w = V1[tid * 32 + c] * inv;
            su += w * w0[c]; sv += w * b0[c];
        }
        u[tid] = su; v[tid] = sv;
    }
    __syncthreads();
    if (tid < 128) {
        float nn = 0.f;
        #pragma unroll
        for (int c = 0; c < 64; ++c) { float t = V2[tid * 64 + c]; nn += t * t; }
        float inv = g2[tid] * rsqrtf(nn);
        float sp = 0.f, sq = 0.f, sr = 0.f;
        #pragma unroll
        for (int c = 0; c < 64; ++c) {
            float w = V2[tid * 64 + c] * inv;
            sp += w * u[c]; sq += w * v[c]; sr += w * b1[c];
        }
        p[tid] = sp; q[tid] = sq; r[tid] = sr;
    }
    __syncthreads();

    // --- single coalesced pass over Vfc row k ---
    const int n3 = tid & 31, og = tid >> 5;
    float nn = 0.f, mk = 0.f, mq = 0.f, mr = 0.f, mb = 0.f;
    #pragma unroll
    for (int i = 0; i < 16; ++i) {
        int o = og + 8 * i;
        float w = Vfc[k * 4096 + tid + 256 * i];
        nn += w * w;
        mk += w * p[o]; mq += w * q[o]; mr += w * r[o]; mb += w * b2[o];
    }
    #pragma unroll
    for (int off = 32; off; off >>= 1) nn += __shfl_xor(nn, off);
    if ((tid & 63) == 0) nnred[tid >> 6] = nn;
    redA[og][n3] = mk; redB[og][n3] = mq; redC[og][n3] = mr; redD[og][n3] = mb;
    __syncthreads();
    if (tid == 0) {
        float s = nnred[0] + nnred[1] + nnred[2] + nnred[3];
        scale_s = gfc[k] * rsqrtf(s);
    }
    __syncthreads();
    if (tid < 32) {
        float smk = 0.f, smq = 0.f, smr = 0.f, smb = 0.f;
        #pragma unroll
        for (int i = 0; i < 8; ++i) {
            smk += redA[i][tid]; smq += redB[i][tid];
            smr += redC[i][tid]; smb += redD[i][tid];
        }
        float scale = scale_s;
        M[tid] = scale * smk;
        float kcp = scale * (smq * T2[tid] + smr * cnt2[tid] + smb);
        #pragma unroll
        for (int off = 16; off; off >>= 1) kcp += __shfl_xor(kcp, off);
        if (tid == 0) Kc_s = kcp + bfc[k];
    }
    __syncthreads();
    if (tid < 32) {
        int b = tid;
        float s = 0.f;
        #pragma unroll
        for (int n = 0; n < 32; ++n) s += M[n] * S2[n * 32 + b];
        out[b * NCLS + k] = s + Kc_s;
    }
}

extern "C" void kernel_launch(void* const* d_in, const int* in_sizes, int n_in,
                              void* d_out, int out_size, void* d_ws, size_t ws_size,
                              hipStream_t stream) {
    const float* x   = (const float*)d_in[0];
    const int* src0  = (const int*)d_in[1];
    const int* dst0  = (const int*)d_in[2];
    const int* src1  = (const int*)d_in[3];
    const int* dst1  = (const int*)d_in[4];
    const int* src2  = (const int*)d_in[5];
    const int* dst2  = (const int*)d_in[6];
    const float* V0  = (const float*)d_in[7];
    const float* g0  = (const float*)d_in[8];
    const float* b0  = (const float*)d_in[9];
    const float* V1  = (const float*)d_in[10];
    const float* g1  = (const float*)d_in[11];
    const float* b1  = (const float*)d_in[12];
    const float* V2  = (const float*)d_in[13];
    const float* g2  = (const float*)d_in[14];
    const float* b2  = (const float*)d_in[15];
    const float* Vfc = (const float*)d_in[16];
    const float* gfc = (const float*)d_in[17];
    const float* bfc = (const float*)d_in[18];

    char* ws = (char*)d_ws;
    _Float16* xt  = (_Float16*)(ws);                 // 200000*32*2 = 12,800,000 B
    _Float16* P0h = (_Float16*)(ws + 12800000);      // 1024*32*2   = 65,536 B
    _Float16* S1h = (_Float16*)(ws + 12865536);      // 256*32*2    = 16,384 B
    float* cnt1   = (float*)(ws + 12881920);         // 256*4       = 1,024 B
    float* S2     = (float*)(ws + 12882944);         // 32*32*4     = 4,096 B
    float* T2     = (float*)(ws + 12887040);         // 32*4        = 128 B
    float* cnt2   = (float*)(ws + 12887168);         // 32*4        = 128 B

    k_transpose<<<(N0 + 63) / 64, 256, 0, stream>>>(x, (h2*)xt);
    k_gather<<<N1, 256, 0, stream>>>((const h8*)xt, src0, dst0, NE0,
                                     P0h, nullptr, nullptr, nullptr, nullptr);
    k_gather<<<N2, 256, 0, stream>>>((const h8*)P0h, src1, dst1, NE1,
                                     S1h, nullptr, nullptr, cnt1, nullptr);
    k_gather<<<N3, 256, 0, stream>>>((const h8*)S1h, src2, dst2, NE2,
                                     nullptr, S2, cnt1, cnt2, T2);
    k_out<<<NCLS, 256, 0, stream>>>(V0, g0, b0, V1, g1, b1, V2, g2, b2,
                                    Vfc, gfc, bfc, S2, T2, cnt2, (float*)d_out);
}

// Round 4
// 81.638 us; speedup vs baseline: 1.7602x; 1.0560x over previous
//
#include <hip/hip_runtime.h>
#include <math.h>

#define N0 200000
#define N1 1024
#define N2 256
#define N3 32
#define NE0 2048000
#define NE1 262144
#define NE2 8192
#define BATCH 32
#define NCLS 10

typedef _Float16 h2 __attribute__((ext_vector_type(2)));
typedef _Float16 h8 __attribute__((ext_vector_type(8)));

__device__ __forceinline__ int lower_bound_i(const int* __restrict__ a, int n, int key) {
    int lo = 0, hi = n;
    while (lo < hi) {
        int mid = (lo + hi) >> 1;
        if (a[mid] < key) lo = mid + 1; else hi = mid;
    }
    return lo;
}

// x (32, 200000) fp32 -> xt (200000, 32) fp16 rows (64 B each), LDS tiled.
__global__ __launch_bounds__(256) void k_transpose(const float* __restrict__ x,
                                                   h2* __restrict__ xt) {
    __shared__ float tile[32][65];
    const int col0 = blockIdx.x * 64;
    const int tid = threadIdx.x;
    const int c = tid & 63, r0 = tid >> 6;       // 4 row-lanes
    #pragma unroll
    for (int r = r0; r < 32; r += 4) {
        int col = col0 + c;
        tile[r][c] = (col < N0) ? x[r * N0 + col] : 0.f;
    }
    __syncthreads();
    const int bb = (tid & 15) * 2, c0 = tid >> 4; // 16 col-lanes, 2 batch rows/thread
    #pragma unroll
    for (int cc = c0; cc < 64; cc += 16) {
        int col = col0 + cc;
        if (col < N0) {
            h2 v;
            v[0] = (_Float16)tile[bb][cc];
            v[1] = (_Float16)tile[bb + 1][cc];
            xt[col * 16 + (bb >> 1)] = v;
        }
    }
}

// Segmented gather-sum over fp16 rows (32 halves = 64 B = 4 x h8).
// out[n][0..31] = sum_{e: dst[e]==n} table[src[e]][0..31], fp32 accumulation.
// One block per output segment (dst sorted, two binary searches).
// Main loop is 4x unrolled: 4 independent src->table load chains in flight
// per thread (latency hiding; gather is L3-latency-bound otherwise).
__global__ __launch_bounds__(256) void k_gather(const h8* __restrict__ table,
                                                const int* __restrict__ src,
                                                const int* __restrict__ dst,
                                                int nedges,
                                                _Float16* __restrict__ out_h,
                                                float* __restrict__ out_f,
                                                const float* __restrict__ cnt_in,
                                                float* __restrict__ cnt_out,
                                                float* __restrict__ t_out) {
    const int n = blockIdx.x;
    const int e0 = lower_bound_i(dst, nedges, n);
    const int e1 = lower_bound_i(dst, nedges, n + 1);
    const int tid = threadIdx.x;
    const int b4 = tid & 3;       // which 16B chunk of the 64B row
    const int g  = tid >> 2;      // 64 edge groups
    float acc[8] = {0.f, 0.f, 0.f, 0.f, 0.f, 0.f, 0.f, 0.f};
    float tacc = 0.f;
    int e = e0 + g;
    // 4x unrolled main loop: independent chains -> 4 table lines in flight.
    for (; e + 192 < e1; e += 256) {
        int s0 = __builtin_nontemporal_load(src + e);
        int s1 = __builtin_nontemporal_load(src + e + 64);
        int s2 = __builtin_nontemporal_load(src + e + 128);
        int s3 = __builtin_nontemporal_load(src + e + 192);
        h8 v0 = table[s0 * 4 + b4];
        h8 v1 = table[s1 * 4 + b4];
        h8 v2 = table[s2 * 4 + b4];
        h8 v3 = table[s3 * 4 + b4];
        #pragma unroll
        for (int i = 0; i < 8; ++i)
            acc[i] += (float)v0[i] + (float)v1[i] + (float)v2[i] + (float)v3[i];
        if (cnt_in != nullptr && b4 == 0)
            tacc += cnt_in[s0] + cnt_in[s1] + cnt_in[s2] + cnt_in[s3];
    }
    for (; e < e1; e += 64) {
        int s = __builtin_nontemporal_load(src + e);
        h8 v = table[s * 4 + b4];
        #pragma unroll
        for (int i = 0; i < 8; ++i) acc[i] += (float)v[i];
        if (cnt_in != nullptr && b4 == 0) tacc += cnt_in[s];
    }
    __shared__ float red[64][33];
    __shared__ float tred[64];
    #pragma unroll
    for (int i = 0; i < 8; ++i) red[g][b4 * 8 + i] = acc[i];
    if (b4 == 0) tred[g] = tacc;
    __syncthreads();
    #pragma unroll
    for (int s = 32; s >= 1; s >>= 1) {
        if (g < s) {
            #pragma unroll
            for (int i = 0; i < 8; ++i)
                red[g][b4 * 8 + i] += red[g + s][b4 * 8 + i];
            if (b4 == 0) tred[g] += tred[g + s];
        }
        __syncthreads();
    }
    if (tid < 32) {
        float v = red[0][tid];
        if (out_h != nullptr) out_h[n * 32 + tid] = (_Float16)v;
        if (out_f != nullptr) out_f[n * 32 + tid] = v;
    } else if (tid == 32 && cnt_out != nullptr) {
        cnt_out[n] = (float)(e1 - e0);
    } else if (tid == 33 && t_out != nullptr) {
        t_out[n] = tred[0];
    }
}

// Weight algebra + final output. One block per class k (10 blocks, 256 threads).
__global__ __launch_bounds__(256) void k_out(
    const float* __restrict__ V0, const float* __restrict__ g0, const float* __restrict__ b0,
    const float* __restrict__ V1, const float* __restrict__ g1, const float* __restrict__ b1,
    const float* __restrict__ V2, const float* __restrict__ g2, const float* __restrict__ b2,
    const float* __restrict__ Vfc, const float* __restrict__ gfc, const float* __restrict__ bfc,
    const float* __restrict__ S2, const float* __restrict__ T2, const float* __restrict__ cnt2,
    float* __restrict__ out) {
    const int k = blockIdx.x;
    const int tid = threadIdx.x;
    __shared__ float w0[32], u[64], v[64], p[128], q[128], r[128];
    __shared__ float redA[8][32], redB[8][32], redC[8][32], redD[8][32];
    __shared__ float nnred[4];
    __shared__ float M[32];
    __shared__ float scale_s, Kc_s;

    // --- weight chain (redundant per block, cheap) ---
    if (tid < 32) {
        float val = V0[tid];
        w0[tid] = g0[tid] * val / fabsf(val);
    }
    __syncthreads();
    if (tid < 64) {
        float nn = 0.f;
        #pragma unroll
        for (int c = 0; c < 32; ++c) { float t = V1[tid * 32 + c]; nn += t * t; }
        float inv = g1[tid] * rsqrtf(nn);
        float su = 0.f, sv = 0.f;
        #pragma unroll
        for (int c = 0; c < 32; ++c) {
            float w = V1[tid * 32 + c] * inv;
            su += w * w0[c]; sv += w * b0[c];
        }
        u[tid] = su; v[tid] = sv;
    }
    __syncthreads();
    if (tid < 128) {
        float nn = 0.f;
        #pragma unroll
        for (int c = 0; c < 64; ++c) { float t = V2[tid * 64 + c]; nn += t * t; }
        float inv = g2[tid] * rsqrtf(nn);
        float sp = 0.f, sq = 0.f, sr = 0.f;
        #pragma unroll
        for (int c = 0; c < 64; ++c) {
            float w = V2[tid * 64 + c] * inv;
            sp += w * u[c]; sq += w * v[c]; sr += w * b1[c];
        }
        p[tid] = sp; q[tid] = sq; r[tid] = sr;
    }
    __syncthreads();

    // --- single coalesced pass over Vfc row k ---
    const int n3 = tid & 31, og = tid >> 5;
    float nn = 0.f, mk = 0.f, mq = 0.f, mr = 0.f, mb = 0.f;
    #pragma unroll
    for (int i = 0; i < 16; ++i) {
        int o = og + 8 * i;
        float w = Vfc[k * 4096 + tid + 256 * i];
        nn += w * w;
        mk += w * p[o]; mq += w * q[o]; mr += w * r[o]; mb += w * b2[o];
    }
    #pragma unroll
    for (int off = 32; off; off >>= 1) nn += __shfl_xor(nn, off);
    if ((tid & 63) == 0) nnred[tid >> 6] = nn;
    redA[og][n3] = mk; redB[og][n3] = mq; redC[og][n3] = mr; redD[og][n3] = mb;
    __syncthreads();
    if (tid == 0) {
        float s = nnred[0] + nnred[1] + nnred[2] + nnred[3];
        scale_s = gfc[k] * rsqrtf(s);
    }
    __syncthreads();
    if (tid < 32) {
        float smk = 0.f, smq = 0.f, smr = 0.f, smb = 0.f;
        #pragma unroll
        for (int i = 0; i < 8; ++i) {
            smk += redA[i][tid]; smq += redB[i][tid];
            smr += redC[i][tid]; smb += redD[i][tid];
        }
        float scale = scale_s;
        M[tid] = scale * smk;
        float kcp = scale * (smq * T2[tid] + smr * cnt2[tid] + smb);
        #pragma unroll
        for (int off = 16; off; off >>= 1) kcp += __shfl_xor(kcp, off);
        if (tid == 0) Kc_s = kcp + bfc[k];
    }
    __syncthreads();
    if (tid < 32) {
        int b = tid;
        float s = 0.f;
        #pragma unroll
        for (int n = 0; n < 32; ++n) s += M[n] * S2[n * 32 + b];
        out[b * NCLS + k] = s + Kc_s;
    }
}

extern "C" void kernel_launch(void* const* d_in, const int* in_sizes, int n_in,
                              void* d_out, int out_size, void* d_ws, size_t ws_size,
                              hipStream_t stream) {
    const float* x   = (const float*)d_in[0];
    const int* src0  = (const int*)d_in[1];
    const int* dst0  = (const int*)d_in[2];
    const int* src1  = (const int*)d_in[3];
    const int* dst1  = (const int*)d_in[4];
    const int* src2  = (const int*)d_in[5];
    const int* dst2  = (const int*)d_in[6];
    const float* V0  = (const float*)d_in[7];
    const float* g0  = (const float*)d_in[8];
    const float* b0  = (const float*)d_in[9];
    const float* V1  = (const float*)d_in[10];
    const float* g1  = (const float*)d_in[11];
    const float* b1  = (const float*)d_in[12];
    const float* V2  = (const float*)d_in[13];
    const float* g2  = (const float*)d_in[14];
    const float* b2  = (const float*)d_in[15];
    const float* Vfc = (const float*)d_in[16];
    const float* gfc = (const float*)d_in[17];
    const float* bfc = (const float*)d_in[18];

    char* ws = (char*)d_ws;
    _Float16* xt  = (_Float16*)(ws);                 // 200000*32*2 = 12,800,000 B
    _Float16* P0h = (_Float16*)(ws + 12800000);      // 1024*32*2   = 65,536 B
    _Float16* S1h = (_Float16*)(ws + 12865536);      // 256*32*2    = 16,384 B
    float* cnt1   = (float*)(ws + 12881920);         // 256*4       = 1,024 B
    float* S2     = (float*)(ws + 12882944);         // 32*32*4     = 4,096 B
    float* T2     = (float*)(ws + 12887040);         // 32*4        = 128 B
    float* cnt2   = (float*)(ws + 12887168);         // 32*4        = 128 B

    k_transpose<<<(N0 + 63) / 64, 256, 0, stream>>>(x, (h2*)xt);
    k_gather<<<N1, 256, 0, stream>>>((const h8*)xt, src0, dst0, NE0,
                                     P0h, nullptr, nullptr, nullptr, nullptr);
    k_gather<<<N2, 256, 0, stream>>>((const h8*)P0h, src1, dst1, NE1,
                                     S1h, nullptr, nullptr, cnt1, nullptr);
    k_gather<<<N3, 256, 0, stream>>>((const h8*)S1h, src2, dst2, NE2,
                                     nullptr, S2, cnt1, cnt2, T2);
    k_out<<<NCLS, 256, 0, stream>>>(V0, g0, b0, V1, g1, b1, V2, g2, b2,
                                    Vfc, gfc, bfc, S2, T2, cnt2, (float*)d_out);
}